// Round 2
// baseline (2469.516 us; speedup 1.0000x reference)
//
#include <hip/hip_runtime.h>

// LSTM forward: B=65536, T=20, I=36, H=30. Gate order i,f,g,o.
// Inputs (fp32): x[B,T,I], W_ih[4H,I], W_hh[4H,H], b_ih[4H], b_hh[4H]
// Output (fp32, concat): out[B,T,H], h_n[1,B,H], c_n[1,B,H]
//
// R4: 4 waves/block (gate per wave) -> 525us, VALUBusy 69%, occ 36%.
// R5: 8 waves per 64-elem block (512 threads): wave w computes 15 rows of
// gate w>>1 (weight pointers stay wave-uniform -> scalar loads). 1024
// blocks x 8 waves = 8192 waves = 8 waves/SIMD (occupancy cap). LDS G
// exchange unchanged; phase-2 combine stays redundant per wave (cheap
// h-broadcast). 4 blocks/CU x 30KB LDS = 120KB <= 160KB.

constexpr int BB = 65536;
constexpr int TT = 20;
constexpr int II = 36;
constexpr int HH = 30;

__device__ __forceinline__ float fast_sigmoid(float v) {
    float e = __expf(-v);                      // v_exp_f32
    return __builtin_amdgcn_rcpf(1.f + e);     // v_rcp_f32
}
__device__ __forceinline__ float fast_tanh(float v) {
    // 1 - 2/(exp(2v)+1): saturates to +/-1, no inf/inf NaN
    float e = __expf(2.f * v);
    return 1.f - 2.f * __builtin_amdgcn_rcpf(e + 1.f);
}

__global__ __launch_bounds__(512, 8) void lstm_fwd(
    const float* __restrict__ x,
    const float* __restrict__ Wih,   // [4H][II] row-major, gate rows i,f,g,o
    const float* __restrict__ Whh,   // [4H][HH]
    const float* __restrict__ bih,   // [4H]
    const float* __restrict__ bhh,   // [4H]
    float* __restrict__ out) {

    __shared__ float G[4 * HH][64];  // [gate row][elem] activated gate values

    const int lane = threadIdx.x & 63;
    const int w = __builtin_amdgcn_readfirstlane((int)(threadIdx.x >> 6)); // 0..7
    const int gate = w >> 1;          // 0..3 (i,f,g,o)
    const int rb = (w & 1) * 15;      // row sub-block within gate
    const int r0 = gate * HH + rb;    // first global gate-row of this wave
    const int b = blockIdx.x * 64 + lane;

    const float* xrow = x + (size_t)b * TT * II;
    float* orow = out + (size_t)b * TT * HH;

    // wave-uniform bases for this wave's 15 gate rows -> s_load path
    const float* wihBase = Wih + (size_t)r0 * II;
    const float* whhBase = Whh + (size_t)r0 * HH;
    const float* bihBase = bih + r0;
    const float* bhhBase = bhh + r0;

    float h[HH], c[HH];
#pragma unroll
    for (int n = 0; n < HH; n++) { h[n] = 0.f; c[n] = 0.f; }

#pragma unroll 1
    for (int t = 0; t < TT; t++) {
        // x row for this timestep: 36 fp32 = 144 B, 16B-aligned (b*2880 + t*144).
        // All 8 waves of the block load the same 64 rows; L1 serves 7 of 8.
        float xr[II];
        const float4* xv = (const float4*)(xrow + t * II);
#pragma unroll
        for (int q = 0; q < II / 4; q++) {
            float4 u = xv[q];
            xr[4 * q + 0] = u.x;
            xr[4 * q + 1] = u.y;
            xr[4 * q + 2] = u.z;
            xr[4 * q + 3] = u.w;
        }

        // phase 1: this wave's 15 gate pre-activations (dual indep FMA chains
        // per row, unroll 2 -> 4 chains to cover 4-cyc dependent latency)
#pragma unroll 2
        for (int n = 0; n < 15; n++) {
            const float* wi = wihBase + n * II;   // wave-uniform
            const float* wh = whhBase + n * HH;   // wave-uniform
            float a0 = bihBase[n] + bhhBase[n];
            float a1 = 0.f;
#pragma unroll
            for (int k = 0; k < II; k++) a0 += wi[k] * xr[k];
#pragma unroll
            for (int k = 0; k < HH; k++) a1 += wh[k] * h[k];
            float a = a0 + a1;
            float v = (gate == 2) ? fast_tanh(a) : fast_sigmoid(a);  // uniform
            G[r0 + n][lane] = v;                  // lane-minor: conflict-free
        }
        __syncthreads();

        // phase 2: every wave redundantly combines -> h,c stay in registers
#pragma unroll
        for (int n = 0; n < HH; n++) {
            float it = G[n][lane];
            float ft = G[HH + n][lane];
            float gt = G[2 * HH + n][lane];
            float ot = G[3 * HH + n][lane];
            float cn = ft * c[n] + it * gt;
            c[n] = cn;
            h[n] = ot * fast_tanh(cn);
        }
        __syncthreads();  // protect G before next timestep's writes

        // store h_t (one wave only; static indices, fire-and-forget)
        if (w == 0) {
            float2* op = (float2*)(orow + t * HH);  // 8B-aligned (b*2400+t*120)
#pragma unroll
            for (int q = 0; q < HH / 2; q++)
                op[q] = make_float2(h[2 * q], h[2 * q + 1]);
        }
    }

    if (w == 0) {
        float* hN = out + (size_t)BB * TT * HH + (size_t)b * HH;
        float* cN = out + (size_t)BB * TT * HH + (size_t)BB * HH + (size_t)b * HH;
        float2* hp = (float2*)hN;
        float2* cp = (float2*)cN;
#pragma unroll
        for (int q = 0; q < HH / 2; q++) {
            hp[q] = make_float2(h[2 * q], h[2 * q + 1]);
            cp[q] = make_float2(c[2 * q], c[2 * q + 1]);
        }
    }
}

extern "C" void kernel_launch(void* const* d_in, const int* in_sizes, int n_in,
                              void* d_out, int out_size, void* d_ws, size_t ws_size,
                              hipStream_t stream) {
    const float* x    = (const float*)d_in[0];
    const float* w_ih = (const float*)d_in[1];
    const float* w_hh = (const float*)d_in[2];
    const float* b_ih = (const float*)d_in[3];
    const float* b_hh = (const float*)d_in[4];
    float* out = (float*)d_out;

    hipLaunchKernelGGL(lstm_fwd, dim3(BB / 64), dim3(512), 0, stream,
                       x, w_ih, w_hh, b_ih, b_hh, out);
}

// Round 3
// 905.095 us; speedup vs baseline: 2.7285x; 2.7285x over previous
//
#include <hip/hip_runtime.h>

// LSTM forward: B=65536, T=20, I=36, H=30. Gate order i,f,g,o.
// Inputs (fp32): x[B,T,I], W_ih[4H,I], W_hh[4H,H], b_ih[4H], b_hh[4H]
// Output (fp32, concat): out[B,T,H], h_n[1,B,H], c_n[1,B,H]
//
// R4: 4 waves/block (gate per wave), G-LDS exchange -> 525us, VALU 69%.
// R5 FAILED: 8 waves/SIMD via launch_bounds(512,8) -> VGPR cap 64 < ~100
//   live state -> scratch spill (FETCH 110MB->3GB), 2364us. Per-thread
//   state floor ~100 VGPR; occupancy is also grid-limited (1024 blocks
//   = 4 blocks/CU exactly). Do NOT cap VGPRs below 128.
// R6 (this): R4 structure + software-pipelined x load (ping-pong float4
//   reg buffers; vmcnt defers to next timestep's use) + 4 independent
//   FMA chains per row (x-dot split 2, h-dot split 2) x unroll-2 rows.

constexpr int BB = 65536;
constexpr int TT = 20;
constexpr int II = 36;
constexpr int HH = 30;

__device__ __forceinline__ float fast_sigmoid(float v) {
    float e = __expf(-v);                      // v_exp_f32
    return __builtin_amdgcn_rcpf(1.f + e);     // v_rcp_f32
}
__device__ __forceinline__ float fast_tanh(float v) {
    // 1 - 2/(exp(2v)+1): saturates to +/-1, no inf/inf NaN
    float e = __expf(2.f * v);
    return 1.f - 2.f * __builtin_amdgcn_rcpf(e + 1.f);
}

// One timestep. XC: current x (float4 regs, already loaded). XN: buffer to
// prefetch x[tcur+1] into (waitcnt for these loads lands at next STEP's
// use -> hidden under phase 2 + barrier). All array indices compile-time.
#define STEP(XC, XN, TCUR)                                                   \
  {                                                                          \
    const int tc_ = (TCUR);                                                  \
    /* phase 1: this wave's gate, 30 rows, 4 indep chains per row */         \
    _Pragma("unroll 2")                                                      \
    for (int n = 0; n < HH; n++) {                                           \
      const float* wi = wihBase + n * II;   /* wave-uniform -> s_load */     \
      const float* wh = whhBase + n * HH;   /* wave-uniform -> s_load */     \
      float s0 = bihBase[n] + bhhBase[n];                                    \
      float s1 = 0.f, s2 = 0.f, s3 = 0.f;                                    \
      _Pragma("unroll")                                                      \
      for (int q = 0; q < II / 4; q++) {                                     \
        float4 u = XC[q];                                                    \
        if ((q & 1) == 0) {                                                  \
          s0 += wi[4*q+0]*u.x; s0 += wi[4*q+1]*u.y;                          \
          s0 += wi[4*q+2]*u.z; s0 += wi[4*q+3]*u.w;                          \
        } else {                                                             \
          s1 += wi[4*q+0]*u.x; s1 += wi[4*q+1]*u.y;                          \
          s1 += wi[4*q+2]*u.z; s1 += wi[4*q+3]*u.w;                          \
        }                                                                    \
      }                                                                      \
      _Pragma("unroll")                                                      \
      for (int k = 0; k < 15; k++) s2 += wh[k] * h[k];                       \
      _Pragma("unroll")                                                      \
      for (int k = 15; k < HH; k++) s3 += wh[k] * h[k];                      \
      float a = (s0 + s1) + (s2 + s3);                                       \
      float v = (gate == 2) ? fast_tanh(a) : fast_sigmoid(a); /* uniform */  \
      G[HH * w + n][lane] = v;              /* lane-minor: conflict-free */  \
    }                                                                        \
    /* prefetch next x: issue here, consume next timestep */                 \
    if (tc_ + 1 < TT) {                                                      \
      const float4* xv_ = (const float4*)(xrow + (tc_ + 1) * II);            \
      _Pragma("unroll")                                                      \
      for (int q = 0; q < II / 4; q++) XN[q] = xv_[q];                       \
    }                                                                        \
    __syncthreads();                                                         \
    /* phase 2: every wave redundantly combines; h,c stay in registers */    \
    _Pragma("unroll")                                                        \
    for (int n = 0; n < HH; n++) {                                           \
      float it = G[n][lane];                                                 \
      float ft = G[HH + n][lane];                                            \
      float gt = G[2 * HH + n][lane];                                        \
      float ot = G[3 * HH + n][lane];                                        \
      float cn = ft * c[n] + it * gt;                                        \
      c[n] = cn;                                                             \
      h[n] = ot * fast_tanh(cn);                                             \
    }                                                                        \
    /* store h_t (one wave; overlaps with barrier wait) */                   \
    if (w == 0) {                                                            \
      float2* op_ = (float2*)(orow + tc_ * HH);                              \
      _Pragma("unroll")                                                      \
      for (int q = 0; q < HH / 2; q++)                                       \
        op_[q] = make_float2(h[2 * q], h[2 * q + 1]);                        \
    }                                                                        \
    __syncthreads();  /* protect G before next timestep's writes */          \
  }

__global__ __launch_bounds__(256, 4) void lstm_fwd(
    const float* __restrict__ x,
    const float* __restrict__ Wih,   // [4H][II] row-major, gate rows i,f,g,o
    const float* __restrict__ Whh,   // [4H][HH]
    const float* __restrict__ bih,   // [4H]
    const float* __restrict__ bhh,   // [4H]
    float* __restrict__ out) {

    __shared__ float G[4 * HH][64];  // [gate row][elem] activated gate values

    const int lane = threadIdx.x & 63;
    const int w = __builtin_amdgcn_readfirstlane((int)(threadIdx.x >> 6)); // 0..3
    const int gate = w;
    const int b = blockIdx.x * 64 + lane;

    const float* xrow = x + (size_t)b * TT * II;
    float* orow = out + (size_t)b * TT * HH;

    // wave-uniform bases for this wave's 30 gate rows -> s_load path
    const float* wihBase = Wih + (size_t)(HH * w) * II;
    const float* whhBase = Whh + (size_t)(HH * w) * HH;
    const float* bihBase = bih + HH * w;
    const float* bhhBase = bhh + HH * w;

    float h[HH], c[HH];
#pragma unroll
    for (int n = 0; n < HH; n++) { h[n] = 0.f; c[n] = 0.f; }

    // x ping-pong buffers: kept as float4 regs so the prefetch's vmcnt
    // defers to the component USE one timestep later.
    float4 xA[II / 4], xB[II / 4];
    {
        const float4* xv = (const float4*)(xrow);  // t=0, 16B-aligned
#pragma unroll
        for (int q = 0; q < II / 4; q++) xA[q] = xv[q];
    }

#pragma unroll 1
    for (int t2 = 0; t2 < TT; t2 += 2) {
        STEP(xA, xB, t2);
        STEP(xB, xA, t2 + 1);
    }

    if (w == 0) {
        float* hN = out + (size_t)BB * TT * HH + (size_t)b * HH;
        float* cN = out + (size_t)BB * TT * HH + (size_t)BB * HH + (size_t)b * HH;
        float2* hp = (float2*)hN;
        float2* cp = (float2*)cN;
#pragma unroll
        for (int q = 0; q < HH / 2; q++) {
            hp[q] = make_float2(h[2 * q], h[2 * q + 1]);
            cp[q] = make_float2(c[2 * q], c[2 * q + 1]);
        }
    }
}

extern "C" void kernel_launch(void* const* d_in, const int* in_sizes, int n_in,
                              void* d_out, int out_size, void* d_ws, size_t ws_size,
                              hipStream_t stream) {
    const float* x    = (const float*)d_in[0];
    const float* w_ih = (const float*)d_in[1];
    const float* w_hh = (const float*)d_in[2];
    const float* b_ih = (const float*)d_in[3];
    const float* b_hh = (const float*)d_in[4];
    float* out = (float*)d_out;

    hipLaunchKernelGGL(lstm_fwd, dim3(BB / 64), dim3(256), 0, stream,
                       x, w_ih, w_hh, b_ih, b_hh, out);
}